// Round 9
// baseline (136.547 us; speedup 1.0000x reference)
//
#include <hip/hip_runtime.h>

// SpectralConv2d: B=2,L=8,C=64,H=64,W=33, M1=M2=16
// Round 8 (resubmit after infra failure): software-pipelined c-loop.
// Diagnosis chain: c-loop = 7.8us/pass, VALUBusy 17% @2 waves/SIMD,
// VGPR=40..52 -> compiler CANNOT hold prefetched loads; each c-iter
// serially exposes ~330cy load latency. Occupancy (r2,r3), L2 locality
// (r4), instr count (r6), cache traffic (r7) all falsified.
// Fix: named-slot register rotation (static indices via full unroll):
//   weights prefetched 4 c-iters ahead (16 float4 in flight),
//   LDS x reads prefetched 2 ahead; __launch_bounds__(256,2) frees VGPRs
//   (LDS/grid cap occupancy at 2 blocks/CU regardless -> registers free).
// Inner mapping = round-6 (2o x 2bl x float4-y per thread, c split 4-way
// across waves): best instr/FMA ratio. Combine redistributed across all
// 256 threads (conflict-free LDS, 2 float4 outputs/thread).
// Staging / decode / zero-fill byte-identical to proven round-1/6 kernels.

constexpr int Cc    = 64;
constexpr int Ww    = 33;
constexpr int HW    = 64 * Ww;        // 2112
constexpr int PLANE = Cc * HW;        // 135168
constexpr int TOT   = 16 * PLANE;     // 2162688 (elements in real half)
constexpr int WSTR  = Cc * 16 * 16;   // 16384: o-stride in weight tensor

#define CFMA(AR, AI, A, B, WRE, WIM)                                \
    AR.x = fmaf(A.x, WRE.x, AR.x); AR.x = fmaf(-B.x, WIM.x, AR.x); \
    AI.x = fmaf(A.x, WIM.x, AI.x); AI.x = fmaf( B.x, WRE.x, AI.x); \
    AR.y = fmaf(A.y, WRE.y, AR.y); AR.y = fmaf(-B.y, WIM.y, AR.y); \
    AI.y = fmaf(A.y, WIM.y, AI.y); AI.y = fmaf( B.y, WRE.y, AI.y); \
    AR.z = fmaf(A.z, WRE.z, AR.z); AR.z = fmaf(-B.z, WIM.z, AR.z); \
    AI.z = fmaf(A.z, WIM.z, AI.z); AI.z = fmaf( B.z, WRE.z, AI.z); \
    AR.w = fmaf(A.w, WRE.w, AR.w); AR.w = fmaf(-B.w, WIM.w, AR.w); \
    AI.w = fmaf(A.w, WIM.w, AI.w); AI.w = fmaf( B.w, WRE.w, AI.w);

__global__ __launch_bounds__(256, 2) void spectral_fused_kernel(
    const float* __restrict__ xr, const float* __restrict__ xi,
    const float* __restrict__ wr1, const float* __restrict__ wi1,
    const float* __restrict__ wr2, const float* __restrict__ wi2,
    float* __restrict__ out)
{
    const int bid = blockIdx.x;
    const int t   = threadIdx.x;

    if (bid < 512) {
        // ---- compute blocks: oq(4) | blq(4) | xrow(16) | corner(2) ----
        const int oq     = bid & 3;
        const int blq    = (bid >> 2) & 3;
        const int xrow   = (bid >> 4) & 15;
        const int corner = bid >> 8;
        const int xin    = corner ? (48 + xrow) : xrow;
        const float* wr  = corner ? wr2 : wr1;
        const float* wi  = corner ? wi2 : wi1;

        // [r(2)][c(64)][blj(4)][y(16)] floats = 8192 floats = 32 KB
        __shared__ __align__(16) float xs[8192];

        // ---- stage x slice: identical to round-1 (proven) ----
        {
            const int y  = t & 15;
            const int wb = (t >> 4) & 3;
            const int cg = t >> 6;
            const int src_base = (blq * 4 + wb) * PLANE + xin * Ww + y;
            #pragma unroll
            for (int k = 0; k < 32; ++k) {
                const int r = k >> 4;
                const int c = ((k & 15) << 2) | cg;
                const float* src = (r ? xi : xr) + (size_t)src_base + c * HW;
                xs[r * 4096 + c * 64 + wb * 16 + y] = *src;
            }
        }
        __syncthreads();

        // ---- compute mapping: yq(2b) | bp(1b) | op(3b) | ch(2b=wave) ----
        const int yq = t & 3;
        const int bp = (t >> 2) & 1;
        const int op = (t >> 3) & 7;
        const int ch = t >> 6;             // wave id = c-chunk
        const int o0 = oq * 16 + op * 2;
        const int cb = ch * 16;

        const float* wrp = wr + o0 * WSTR + xrow * 16 + yq * 4;
        const float* wip = wi + o0 * WSTR + xrow * 16 + yq * 4;
        const float4* xsr = reinterpret_cast<const float4*>(xs) + bp * 8 + yq;
        const float4* xsi = xsr + 1024;

        float4 ar[2][2], ai[2][2];
        #pragma unroll
        for (int i = 0; i < 2; ++i)
            #pragma unroll
            for (int j = 0; j < 2; ++j) {
                ar[i][j] = make_float4(0.f, 0.f, 0.f, 0.f);
                ai[i][j] = make_float4(0.f, 0.f, 0.f, 0.f);
            }

        // ---- software-pipelined c-loop: weights D=4 ahead, LDS D=2 ahead.
        // All slot indices static (full unroll) -> stays in registers.
        float4 wreb[4][2], wimb[4][2], ab[2][2], bb[2][2];
        #pragma unroll
        for (int p = 0; p < 4; ++p) {
            const int c = cb + p;
            wreb[p][0] = *reinterpret_cast<const float4*>(wrp + c * 256);
            wreb[p][1] = *reinterpret_cast<const float4*>(wrp + WSTR + c * 256);
            wimb[p][0] = *reinterpret_cast<const float4*>(wip + c * 256);
            wimb[p][1] = *reinterpret_cast<const float4*>(wip + WSTR + c * 256);
        }
        #pragma unroll
        for (int p = 0; p < 2; ++p) {
            const int c = cb + p;
            ab[p][0] = xsr[c * 16];     ab[p][1] = xsr[c * 16 + 4];
            bb[p][0] = xsi[c * 16];     bb[p][1] = xsi[c * 16 + 4];
        }

        #pragma unroll
        for (int cc = 0; cc < 16; ++cc) {
            const int ws = cc & 3;          // weight slot (static)
            const int xl = cc & 1;          // lds slot (static)
            const float4 wre0 = wreb[ws][0], wre1 = wreb[ws][1];
            const float4 wim0 = wimb[ws][0], wim1 = wimb[ws][1];
            const float4 a0 = ab[xl][0], a1 = ab[xl][1];
            const float4 b0 = bb[xl][0], b1 = bb[xl][1];

            if (cc + 4 < 16) {              // refill weight slot
                const int c = cb + cc + 4;
                wreb[ws][0] = *reinterpret_cast<const float4*>(wrp + c * 256);
                wreb[ws][1] = *reinterpret_cast<const float4*>(wrp + WSTR + c * 256);
                wimb[ws][0] = *reinterpret_cast<const float4*>(wip + c * 256);
                wimb[ws][1] = *reinterpret_cast<const float4*>(wip + WSTR + c * 256);
            }
            if (cc + 2 < 16) {              // refill lds slot
                const int c = cb + cc + 2;
                ab[xl][0] = xsr[c * 16];    ab[xl][1] = xsr[c * 16 + 4];
                bb[xl][0] = xsi[c * 16];    bb[xl][1] = xsi[c * 16 + 4];
            }

            CFMA(ar[0][0], ai[0][0], a0, b0, wre0, wim0)
            CFMA(ar[0][1], ai[0][1], a1, b1, wre0, wim0)
            CFMA(ar[1][0], ai[1][0], a0, b0, wre1, wim1)
            CFMA(ar[1][1], ai[1][1], a1, b1, wre1, wim1)
        }

        // ---- park ALL partials in xs: sc[ch][k2(8)][tile(64)] f4 = 32KB ----
        __syncthreads();                    // all xs reads complete
        {
            float4* sc = reinterpret_cast<float4*>(xs);
            const int tile = t & 63;
            #pragma unroll
            for (int k2 = 0; k2 < 8; ++k2) {
                const int ri = k2 >> 2, i = (k2 >> 1) & 1, j = k2 & 1;
                const float4 v = ri ? ai[i][j] : ar[i][j];
                sc[ch * 512 + k2 * 64 + tile] = v;      // lane-consecutive
            }
        }
        __syncthreads();

        // ---- reduce + store: ALL 256 threads, 2 float4 outputs each ----
        {
            const float4* sc = reinterpret_cast<const float4*>(xs);
            #pragma unroll
            for (int q = 0; q < 2; ++q) {
                const int m    = t + q * 256;   // [0,512)
                const int tile = m & 63;
                const int k2   = m >> 6;        // 0..7
                float4 acc = sc[k2 * 64 + tile];
                #pragma unroll
                for (int p = 1; p < 4; ++p) {
                    const float4 pr = sc[p * 512 + k2 * 64 + tile];
                    acc.x += pr.x; acc.y += pr.y; acc.z += pr.z; acc.w += pr.w;
                }
                const int yq_ = tile & 3;
                const int bp_ = (tile >> 2) & 1;
                const int op_ = (tile >> 3) & 7;
                const int ri  = k2 >> 2;
                const int o   = oq * 16 + op_ * 2 + ((k2 >> 1) & 1);
                const int bl  = blq * 4 + bp_ * 2 + (k2 & 1);
                const size_t ob = (size_t)(bl * Cc + o) * HW
                                + (size_t)xin * Ww + yq_ * 4
                                + (ri ? (size_t)TOT : 0);
                out[ob + 0] = acc.x; out[ob + 1] = acc.y;
                out[ob + 2] = acc.z; out[ob + 3] = acc.w;
            }
        }

        // ---- zero y in [16,33) tails: 16 o x 4 bl x 17 y x 2 ri = 2176 ----
        #pragma unroll
        for (int q = 0; q < 9; ++q) {
            const int k = t + q * 256;
            if (k < 2176) {
                const int ri   = k >= 1088;
                const int rem  = ri ? (k - 1088) : k;
                const int ol_  = rem / 68;            // local o (0..15)
                const int sub  = rem - ol_ * 68;      // 68 = 4 bl * 17 y
                const int blj_ = sub / 17;
                const int yy   = 16 + (sub - blj_ * 17);
                const size_t idx = (size_t)((blq * 4 + blj_) * Cc + oq * 16 + ol_) * HW
                                 + (size_t)xin * Ww + yy + (ri ? (size_t)TOT : 0);
                out[idx] = 0.f;
            }
        }
    } else {
        // ---- zero blocks: one per (ri, bl, o) plane, middle rows h in [16,48)
        // 1056 contiguous floats at plane*2112 + 528 -> 264 float4.
        const int p     = bid - 512;          // [0, 2048)
        const int ri    = p >> 10;
        const int plane = p & 1023;           // bl*64 + o
        float4* dst = (float4*)(out + (size_t)ri * TOT + (size_t)plane * HW + 528);
        const float4 z = make_float4(0.f, 0.f, 0.f, 0.f);
        dst[t] = z;
        if (t < 8) dst[256 + t] = z;          // 264 = 256 + 8
    }
}

extern "C" void kernel_launch(void* const* d_in, const int* in_sizes, int n_in,
                              void* d_out, int out_size, void* d_ws, size_t ws_size,
                              hipStream_t stream) {
    const float* xr  = (const float*)d_in[0];
    const float* xi  = (const float*)d_in[1];
    const float* wr1 = (const float*)d_in[2];
    const float* wi1 = (const float*)d_in[3];
    const float* wr2 = (const float*)d_in[4];
    const float* wi2 = (const float*)d_in[5];
    float* out = (float*)d_out;

    spectral_fused_kernel<<<2560, 256, 0, stream>>>(xr, xi, wr1, wi1, wr2, wi2, out);
}

// Round 10
// 96.955 us; speedup vs baseline: 1.4084x; 1.4084x over previous
//
#include <hip/hip_runtime.h>

// SpectralConv2d: B=2,L=8,C=64,H=64,W=33, M1=M2=16
// Round 10: round-1 kernel (proven best, 93.4us) + named-slot software
// pipelining of the c-loop ONLY. r9 failed on VGPR spills (demand ~150 at
// cap 128 -> +102MB scratch traffic: WRITE 85MB, FETCH 67MB); this build
// keeps r1's small mapping (1o x 1bl x float4-y per thread, acc = 8 VGPR)
// so total register demand ~80:
//   weights prefetched D=4 iters ahead (wreb[4]+wimb[4] = 32 VGPR),
//   LDS x reads prefetched D=2 ahead  (ab[2]+bb[2]     = 16 VGPR).
// Full 64-iter unroll keeps slot indices static (registers, not scratch).
// __launch_bounds__(256,2): VGPR cap 256 (grid = 2 blocks/CU anyway).
// NO combine epilogue, NO remap: everything else byte-identical to r1.
// Mechanism under test: per-wave serial load->use chain (~290cy/iter)
// is the c-loop's 7.8us; D=4/D=2 rotation cuts per-iter wall to ~75cy.
// Predicted: WRITE back to ~17.2MB, FETCH ~33MB, kernel ~18-19us,
// total ~87-89us. If within +-1.5us of 93.4: mechanism falsified, ceiling.

constexpr int Cc    = 64;
constexpr int Ww    = 33;
constexpr int HW    = 64 * Ww;        // 2112
constexpr int PLANE = Cc * HW;        // 135168
constexpr int TOT   = 16 * PLANE;     // 2162688 (elements in real half)
constexpr int WSTR  = Cc * 16 * 16;   // 16384: o-stride in weight tensor

__global__ __launch_bounds__(256, 2) void spectral_fused_kernel(
    const float* __restrict__ xr, const float* __restrict__ xi,
    const float* __restrict__ wr1, const float* __restrict__ wi1,
    const float* __restrict__ wr2, const float* __restrict__ wi2,
    float* __restrict__ out)
{
    const int bid = blockIdx.x;
    const int t   = threadIdx.x;

    if (bid < 512) {
        // ---- compute blocks: oq(4) | blq(4) | xrow(16) | corner(2) ----
        const int oq     = bid & 3;
        const int blq    = (bid >> 2) & 3;
        const int xrow   = (bid >> 4) & 15;
        const int corner = bid >> 8;
        const int xin    = corner ? (48 + xrow) : xrow;
        const float* wr  = corner ? wr2 : wr1;
        const float* wi  = corner ? wi2 : wi1;

        // [r(2)][c(64)][blj(4)][y(16)] floats = 8192 floats = 32 KB
        __shared__ __align__(16) float xs[8192];

        // ---- stage x slice: coalesced scalar loads (identical to r1) ----
        {
            const int y  = t & 15;
            const int wb = (t >> 4) & 3;
            const int cg = t >> 6;
            const int src_base = (blq * 4 + wb) * PLANE + xin * Ww + y;
            #pragma unroll
            for (int k = 0; k < 32; ++k) {
                const int r = k >> 4;
                const int c = ((k & 15) << 2) | cg;
                const float* src = (r ? xi : xr) + (size_t)src_base + c * HW;
                xs[r * 4096 + c * 64 + wb * 16 + y] = *src;
            }
        }
        __syncthreads();

        // ---- compute: thread = (yq, blj, ol), identical mapping to r1 ----
        const int yq  = t & 3;
        const int blj = (t >> 2) & 3;
        const int ol  = t >> 4;
        const int o   = oq * 16 + ol;
        const int bl  = blq * 4 + blj;

        const float* wrp = wr + o * WSTR + xrow * 16 + yq * 4;  // + c*256
        const float* wip = wi + o * WSTR + xrow * 16 + yq * 4;
        const float4* xsr = reinterpret_cast<const float4*>(xs) + blj * 4 + yq;
        const float4* xsi = xsr + 1024;    // imag half

        float4 ar = make_float4(0.f, 0.f, 0.f, 0.f);
        float4 ai = make_float4(0.f, 0.f, 0.f, 0.f);

        // ---- software-pipelined c-loop: weights D=4 ahead, LDS D=2 ahead.
        float4 wreb[4], wimb[4], ab[2], bb[2];
        #pragma unroll
        for (int p = 0; p < 4; ++p) {
            wreb[p] = *reinterpret_cast<const float4*>(wrp + p * 256);
            wimb[p] = *reinterpret_cast<const float4*>(wip + p * 256);
        }
        #pragma unroll
        for (int p = 0; p < 2; ++p) {
            ab[p] = xsr[p * 16];
            bb[p] = xsi[p * 16];
        }

        #pragma unroll
        for (int c = 0; c < Cc; ++c) {
            const int ws = c & 3;              // weight slot (static index)
            const int xl = c & 1;              // lds slot (static index)
            const float4 wre = wreb[ws], wim = wimb[ws];
            const float4 a   = ab[xl],   b   = bb[xl];

            if (c + 4 < Cc) {                  // refill weight slot
                wreb[ws] = *reinterpret_cast<const float4*>(wrp + (c + 4) * 256);
                wimb[ws] = *reinterpret_cast<const float4*>(wip + (c + 4) * 256);
            }
            if (c + 2 < Cc) {                  // refill lds slot
                ab[xl] = xsr[(c + 2) * 16];
                bb[xl] = xsi[(c + 2) * 16];
            }

            ar.x = fmaf(a.x, wre.x, ar.x); ar.x = fmaf(-b.x, wim.x, ar.x);
            ai.x = fmaf(a.x, wim.x, ai.x); ai.x = fmaf( b.x, wre.x, ai.x);
            ar.y = fmaf(a.y, wre.y, ar.y); ar.y = fmaf(-b.y, wim.y, ar.y);
            ai.y = fmaf(a.y, wim.y, ai.y); ai.y = fmaf( b.y, wre.y, ai.y);
            ar.z = fmaf(a.z, wre.z, ar.z); ar.z = fmaf(-b.z, wim.z, ar.z);
            ai.z = fmaf(a.z, wim.z, ai.z); ai.z = fmaf( b.z, wre.z, ai.z);
            ar.w = fmaf(a.w, wre.w, ar.w); ar.w = fmaf(-b.w, wim.w, ar.w);
            ai.w = fmaf(a.w, wim.w, ai.w); ai.w = fmaf( b.w, wre.w, ai.w);
        }

        const size_t ob = (size_t)(bl * Cc + o) * HW + (size_t)xin * Ww + yq * 4;
        out[ob + 0] = ar.x; out[ob + 1] = ar.y;
        out[ob + 2] = ar.z; out[ob + 3] = ar.w;
        out[TOT + ob + 0] = ai.x; out[TOT + ob + 1] = ai.y;
        out[TOT + ob + 2] = ai.z; out[TOT + ob + 3] = ai.w;

        // ---- zero y in [16,33) tails: 16 o x 4 bl x 17 y x 2 ri = 2176 ----
        #pragma unroll
        for (int q = 0; q < 9; ++q) {
            const int k = t + q * 256;
            if (k < 2176) {
                const int ri   = k >= 1088;
                const int rem  = ri ? (k - 1088) : k;
                const int ol_  = rem / 68;            // local o (0..15)
                const int sub  = rem - ol_ * 68;      // 68 = 4 bl * 17 y
                const int blj_ = sub / 17;
                const int yy   = 16 + (sub - blj_ * 17);
                const size_t idx = (size_t)((blq * 4 + blj_) * Cc + oq * 16 + ol_) * HW
                                 + (size_t)xin * Ww + yy + (ri ? (size_t)TOT : 0);
                out[idx] = 0.f;
            }
        }
    } else {
        // ---- zero blocks: one per (ri, bl, o) plane, middle rows h in [16,48)
        // 1056 contiguous floats at plane*2112 + 528 -> 264 float4.
        const int p     = bid - 512;          // [0, 2048)
        const int ri    = p >> 10;
        const int plane = p & 1023;           // bl*64 + o
        float4* dst = (float4*)(out + (size_t)ri * TOT + (size_t)plane * HW + 528);
        const float4 z = make_float4(0.f, 0.f, 0.f, 0.f);
        dst[t] = z;
        if (t < 8) dst[256 + t] = z;          // 264 = 256 + 8
    }
}

extern "C" void kernel_launch(void* const* d_in, const int* in_sizes, int n_in,
                              void* d_out, int out_size, void* d_ws, size_t ws_size,
                              hipStream_t stream) {
    const float* xr  = (const float*)d_in[0];
    const float* xi  = (const float*)d_in[1];
    const float* wr1 = (const float*)d_in[2];
    const float* wi1 = (const float*)d_in[3];
    const float* wr2 = (const float*)d_in[4];
    const float* wi2 = (const float*)d_in[5];
    float* out = (float*)d_out;

    spectral_fused_kernel<<<2560, 256, 0, stream>>>(xr, xi, wr1, wi1, wr2, wi2, out);
}